// Round 9
// baseline (37.880 us; speedup 1.0000x reference)
//
#include <hip/hip_runtime.h>
#include <hip/hip_bf16.h>

// NT-Xent (SimCLR) loss: B=4096, D=128, N=8192, TEMP=0.5.
// Round 9: 128x128 tile pairs (4x work per tile-section; sections 8448->2080)
// to amortize the per-section fixed costs that have pinned MfmaUtil at ~13%
// across all structures. Block: cached 128-row c-tile in regs (16 bfrag/wave),
// streams 128-row partners through 2x32KB LDS (global_load_lds 16B + XOR
// swizzle via pre-swizzled source). 576 blocks, 2 blocks/CU.

typedef short bfrag __attribute__((ext_vector_type(8)));   // 8 bf16 (4 VGPRs)
typedef float f32x4 __attribute__((ext_vector_type(4)));

static __device__ __forceinline__ unsigned short f2bf_rne(float x) {
    unsigned u = __float_as_uint(x);
    return (unsigned short)((u + 0x7fffu + ((u >> 16) & 1u)) >> 16);
}
static __device__ __forceinline__ float bf2f(unsigned short b) {
    return __uint_as_float(((unsigned)b) << 16);
}

// ------ kernel 1: normalize pair (i, i+B); emit zn/bf16, diag, pos; zero sumexp
__global__ __launch_bounds__(256) void nt_norm_pair(
        const float* __restrict__ zi, const float* __restrict__ zj,
        unsigned short* __restrict__ zn, float* __restrict__ diag,
        float* __restrict__ pos, float* __restrict__ sumexp) {
    constexpr int B = 4096, D = 128;
    const int wave = threadIdx.x >> 6, lane = threadIdx.x & 63;
    const int p = blockIdx.x * 4 + wave;                   // 0..4095
    float2 a = reinterpret_cast<const float2*>(zi + (size_t)p * D)[lane];
    float2 b = reinterpret_cast<const float2*>(zj + (size_t)p * D)[lane];
    float sa = a.x * a.x + a.y * a.y;
    float sb = b.x * b.x + b.y * b.y;
    #pragma unroll
    for (int m = 32; m; m >>= 1) { sa += __shfl_xor(sa, m); sb += __shfl_xor(sb, m); }
    float ia = 1.f / fmaxf(sqrtf(sa), 1e-8f);
    float ib = 1.f / fmaxf(sqrtf(sb), 1e-8f);
    unsigned short a0 = f2bf_rne(a.x * ia), a1 = f2bf_rne(a.y * ia);
    unsigned short b0 = f2bf_rne(b.x * ib), b1 = f2bf_rne(b.y * ib);
    float fa0 = bf2f(a0), fa1 = bf2f(a1), fb0 = bf2f(b0), fb1 = bf2f(b1);
    float da = fa0 * fa0 + fa1 * fa1;                      // bf16 self-dot (matches MFMA diag)
    float db = fb0 * fb0 + fb1 * fb1;
    float cr = fa0 * fb0 + fa1 * fb1;                      // bf16 cross-dot (positive pair)
    #pragma unroll
    for (int m = 32; m; m >>= 1) {
        da += __shfl_xor(da, m); db += __shfl_xor(db, m); cr += __shfl_xor(cr, m);
    }
    reinterpret_cast<unsigned*>(zn + (size_t)p * D)[lane] =
        (unsigned)a0 | ((unsigned)a1 << 16);
    reinterpret_cast<unsigned*>(zn + (size_t)(p + B) * D)[lane] =
        (unsigned)b0 | ((unsigned)b1 << 16);
    if (lane == 0) {
        diag[p] = da; diag[p + B] = db;
        pos[p] = 2.f * cr; pos[p + B] = 2.f * cr;          // sim symmetric
        sumexp[p] = 0.f; sumexp[p + B] = 0.f;              // replaces hipMemsetAsync
    }
}

// ------ kernel 2: strip-mined symmetric gram, 128x128 tiles ----------------
// grid (64, 9): c = blockIdx.x is the cached 128-row tile. y=0: self-tile
// (d=0, T=1, cw=0). y=1..8: T=4 streamed tiles at d = 4(y-1)+1 .. 4(y-1)+4;
// d=32 (y==8, t==3) only for c<32 (T=3 for c>=32). 2080 tile-computes total.
// acc[fj][fi] = sim[j in cached c][i in streamed]. 4 waves = 2x2 quadrants.
__global__ __launch_bounds__(256, 2) void nt_gram_sym(
        const unsigned short* __restrict__ zn, float* __restrict__ sumexp) {
    const int c = blockIdx.x;
    const int y = blockIdx.y;
    const int T  = (y == 0) ? 1 : ((y == 8 && c >= 32) ? 3 : 4);
    const int d0 = (y == 0) ? 0 : 4 * (y - 1) + 1;

    __shared__ short buf[2][128][128];                     // 2 x 32 KB stream buffers

    const short* zs = (const short*)zn;
    const int tid = threadIdx.x, wid = tid >> 6, lane = tid & 63;
    const int wj = wid >> 1, wi = wid & 1;                 // wave quadrant (64x64)
    const int lr = lane & 15, lk = lane >> 4;

    // cached A-frags (tile c, this wave's 64 j-rows), direct from L2
    bfrag ca[4][4];                                        // [ks][f]
    {
        const int rbase = c * 128 + wj * 64;
        #pragma unroll
        for (int ks = 0; ks < 4; ++ks)
            #pragma unroll
            for (int f = 0; f < 4; ++f)
                ca[ks][f] = *reinterpret_cast<const bfrag*>(
                    zs + (size_t)(rbase + f * 16 + lr) * 128 + ks * 32 + lk * 8);
    }
    asm volatile("s_waitcnt vmcnt(0)" ::: "memory");       // drain ca: clean vmcnt base

    // stage streamed 128-row tile t into buf[slot]: 2048 x 16B chunks, 8/thread.
    // LDS linear; global source pre-swizzled: LDS (r, cpos) holds chunk cpos^(r&7).
    auto STAGE = [&](int t, int slot) {
        const int srow = ((c + d0 + t) & 63) * 128;
        #pragma unroll
        for (int q = 0; q < 8; ++q) {
            const int cbase = (q * 4 + wid) * 64;          // wave-uniform
            const int chunk = cbase + lane;                // 0..2047
            const int r = chunk >> 4;                      // 0..127
            const int cpos = chunk & 15;
            const int csrc = cpos ^ (r & 7);
            const short* g = zs + (size_t)(srow + r) * 128 + csrc * 8;
            __builtin_amdgcn_global_load_lds(
                (const __attribute__((address_space(1))) void*)g,
                (__attribute__((address_space(3))) void*)(
                    &buf[slot][0][0] + (size_t)cbase * 8),
                16, 0, 0);
        }
    };

    STAGE(0, 0);

    constexpr float K_E = 2.8853900817779268f;             // 2 * log2(e)
    float jp[16];
    #pragma unroll
    for (int q = 0; q < 16; ++q) jp[q] = 0.f;

    for (int t = 0; t < T; ++t) {
        const bool more = (t + 1 < T);
        if (more) STAGE(t + 1, (t + 1) & 1);
        // Counted waits: STAGE(t) complete; up to 4 prior epilogue atomic
        // instrs + STAGE(t+1)'s 8 loads stay in flight.
        if (t == 0) {
            if (more) asm volatile("s_waitcnt vmcnt(8)" ::: "memory");
            else      asm volatile("s_waitcnt vmcnt(0)" ::: "memory");
        } else {
            if (more) asm volatile("s_waitcnt vmcnt(12)" ::: "memory");
            else      asm volatile("s_waitcnt vmcnt(4)" ::: "memory");
        }
        __builtin_amdgcn_s_barrier();

        // ---- compute tile t from buf[t&1]: 64 MFMA per wave ----
        const int srow = ((c + d0 + t) & 63) * 128;        // streamed base row (i side)
        f32x4 acc[4][4] = {};                              // [fj][fi]
        #pragma unroll
        for (int ks = 0; ks < 4; ++ks) {
            bfrag cb[4];
            #pragma unroll
            for (int f = 0; f < 4; ++f) {
                const int r = wi * 64 + f * 16 + lr;
                const int cc = (ks * 4 + lk) ^ (lr & 7);   // swizzled chunk index
                cb[f] = *reinterpret_cast<const bfrag*>(&buf[t & 1][r][cc * 8]);
            }
            #pragma unroll
            for (int fj = 0; fj < 4; ++fj)
                #pragma unroll
                for (int fi = 0; fi < 4; ++fi)
                    acc[fj][fi] = __builtin_amdgcn_mfma_f32_16x16x32_bf16(
                        ca[ks][fj], cb[fi], acc[fj][fi], 0, 0, 0);
        }

        const float cw = (d0 + t) ? 1.f : 0.f;             // self-tile: no col weight
        #pragma unroll
        for (int fi = 0; fi < 4; ++fi) {
            float s = 0.f;
            #pragma unroll
            for (int fj = 0; fj < 4; ++fj)
                #pragma unroll
                for (int r = 0; r < 4; ++r) {
                    const float e = exp2f(acc[fj][fi][r] * K_E);
                    s += e;
                    jp[fj * 4 + r] += e * cw;              // j-col partial (reg, whole strip)
                }
            s += __shfl_xor(s, 16);                        // i-row sum over lk groups
            s += __shfl_xor(s, 32);
            if (lk == 0) atomicAdd(&sumexp[srow + wi * 64 + fi * 16 + lr], s);
        }
        __builtin_amdgcn_s_barrier();                      // all waves done with buf[t&1]
    }

    // ---- once per block: reduce j-col partials over 16 lr lanes ----
    // 16 independent 4-shfl chains; then ONE 64-lane atomic (distinct rows).
    float myv = 0.f;
    #pragma unroll
    for (int tt = 0; tt < 16; ++tt) {
        float v = jp[tt];
        v += __shfl_xor(v, 1);
        v += __shfl_xor(v, 2);
        v += __shfl_xor(v, 4);
        v += __shfl_xor(v, 8);
        if (lr == tt) myv = v;                             // designated writer per (fj,r)
    }
    // lane (lk, lr) writes row fj*16 + lk*4 + r with fj = lr>>2, r = lr&3
    atomicAdd(&sumexp[c * 128 + wj * 64 + (lr >> 2) * 16 + lk * 4 + (lr & 3)], myv);
}

// ------ kernel 3: finalize scalar ------------------------------------------
__global__ __launch_bounds__(1024) void nt_finalize(
        const float* __restrict__ sumexp, const float* __restrict__ diag,
        const float* __restrict__ pos, float* __restrict__ out) {
    constexpr int N = 8192;
    constexpr float K_E = 2.8853900817779268f;
    float s = 0.f;
    for (int i = threadIdx.x; i < N; i += 1024)
        s += __logf(sumexp[i] - exp2f(diag[i] * K_E)) - pos[i];
    #pragma unroll
    for (int m = 32; m; m >>= 1) s += __shfl_xor(s, m);
    __shared__ float red[16];
    if ((threadIdx.x & 63) == 0) red[threadIdx.x >> 6] = s;
    __syncthreads();
    if (threadIdx.x == 0) {
        float t = 0.f;
        #pragma unroll
        for (int w = 0; w < 16; ++w) t += red[w];
        out[0] = t * (1.0f / (float)N);
    }
}

extern "C" void kernel_launch(void* const* d_in, const int* in_sizes, int n_in,
                              void* d_out, int out_size, void* d_ws, size_t ws_size,
                              hipStream_t stream) {
    const float* zi = (const float*)d_in[0];
    const float* zj = (const float*)d_in[1];
    float* out = (float*)d_out;

    char* ws = (char*)d_ws;
    unsigned short* zn = (unsigned short*)ws;                    // 2 MB
    float* sumexp = (float*)(ws + 2 * 1024 * 1024);              // 32 KB
    float* diag   = (float*)(ws + 2 * 1024 * 1024 + 1 * 32768);  // 32 KB
    float* pos    = (float*)(ws + 2 * 1024 * 1024 + 2 * 32768);  // 32 KB

    nt_norm_pair<<<1024, 256, 0, stream>>>(zi, zj, zn, diag, pos, sumexp);
    nt_gram_sym<<<dim3(64, 9), 256, 0, stream>>>(zn, sumexp);
    nt_finalize<<<1, 1024, 0, stream>>>(sumexp, diag, pos, out);
}